// Round 2
// baseline (119.489 us; speedup 1.0000x reference)
//
#include <hip/hip_runtime.h>
#include <hip/hip_bf16.h>

#define SQ 2048
#define NBATCH 2
#define NHEAD 16
#define DHEAD 128
#define SCALE 0.08838834764831845f

typedef _Float16 f16x8 __attribute__((ext_vector_type(8)));
typedef float f32x4 __attribute__((ext_vector_type(4)));

static __device__ __forceinline__ _Float16 f2h(float f) { return (_Float16)f; }

typedef struct { _Float16 x, y, z, w; } h4;

__global__ __launch_bounds__(256)
void attn_fwd(const float* __restrict__ q, const float* __restrict__ k,
              const float* __restrict__ v, const float* __restrict__ sinks,
              float* __restrict__ out) {
    // LDS: K row-major [64][128], V transposed [128][64], P per-wave [16][64]
    __shared__ _Float16 Klds[64 * 128];
    __shared__ _Float16 Vlds[128 * 64];
    __shared__ _Float16 Plds[4][16 * 64];

    const int tid  = threadIdx.x;
    const int w    = tid >> 6;        // wave 0..3
    const int lane = tid & 63;
    const int r    = lane & 15;       // q-row within wave tile (S^T col)
    const int g    = lane >> 4;       // lane group 0..3

    const int bid = blockIdx.x;
    const int b   = bid & 1;
    const int h   = (bid >> 1) & 15;
    const int qt  = bid >> 5;
    const int q0  = qt * 64;

    const int sq = q0 + w * 16 + r;   // this lane's q-row (for its S values)

    // ---- Load Q fragments (held in regs for whole kernel) ----
    // A/B frag layout for 16x16x32: lane supplies row/col (lane&15),
    // k = (lane>>4)*8 + j  (8 contiguous k per lane -> vector load)
    f16x8 qf[4];
    {
        const float* qrow = q + ((size_t)sq * NBATCH + b) * (NHEAD * DHEAD) + h * DHEAD;
        #pragma unroll
        for (int kc = 0; kc < 4; ++kc) {
            const int d0 = kc * 32 + g * 8;
            f32x4 a = *(const f32x4*)(qrow + d0);
            f32x4 c = *(const f32x4*)(qrow + d0 + 4);
            f16x8 t;
            t[0] = f2h(a.x); t[1] = f2h(a.y); t[2] = f2h(a.z); t[3] = f2h(a.w);
            t[4] = f2h(c.x); t[5] = f2h(c.y); t[6] = f2h(c.z); t[7] = f2h(c.w);
            qf[kc] = t;
        }
    }

    float m_run = sinks[h];   // running max initialized to sink logit
    float l_run = 1.0f;       // sink contributes exp(sink - m) = 1 at init
    f32x4 acc[8];
    #pragma unroll
    for (int i = 0; i < 8; ++i) acc[i] = (f32x4)(0.0f);

    const int ntiles = (q0 >> 6) + 1;   // causal: only tiles with kt <= q0
    for (int it = 0; it < ntiles; ++it) {
        const int kt = it << 6;
        __syncthreads();   // protect LDS from previous iteration's readers

        // ---- stage K tile [64][128] (coalesced), swizzled ----
        {
            const float* kbase = k + (size_t)b * DHEAD + (size_t)kt * (NBATCH * DHEAD);
            #pragma unroll
            for (int i = 0; i < 8; ++i) {
                const int id4 = tid + i * 256;         // 2048 float4 chunks
                const int row = id4 >> 5;              // 32 float4 per row
                const int c0  = (id4 & 31) << 2;
                f32x4 a = *(const f32x4*)(kbase + (size_t)row * (NBATCH * DHEAD) + c0);
                const int e = (row * 128 + c0) ^ ((row & 7) << 3);
                h4 pk = { f2h(a.x), f2h(a.y), f2h(a.z), f2h(a.w) };
                *(h4*)(&Klds[e]) = pk;
            }
        }
        // ---- stage V transposed -> Vlds[d][c] (reads coalesced per c-row) ----
        {
            const float* vbase = v + (size_t)b * DHEAD;
            const int d  = tid & 127;
            const int cg = tid >> 7;
            #pragma unroll
            for (int pass = 0; pass < 8; ++pass) {
                const int c0 = pass * 8 + cg * 4;
                float a0 = vbase[(size_t)(kt + c0 + 0) * (NBATCH * DHEAD) + d];
                float a1 = vbase[(size_t)(kt + c0 + 1) * (NBATCH * DHEAD) + d];
                float a2 = vbase[(size_t)(kt + c0 + 2) * (NBATCH * DHEAD) + d];
                float a3 = vbase[(size_t)(kt + c0 + 3) * (NBATCH * DHEAD) + d];
                const int e = (d * 64 + c0) ^ ((d & 7) << 3);
                h4 pk = { f2h(a0), f2h(a1), f2h(a2), f2h(a3) };
                *(h4*)(&Vlds[e]) = pk;
            }
        }
        __syncthreads();

        // ---- S^T = K * Q^T : lane holds S[q-row r][c = ct*16 + g*4 + i] ----
        float s[16];
        #pragma unroll
        for (int ct = 0; ct < 4; ++ct) {
            f32x4 sa = (f32x4)(0.0f);
            const int c = ct * 16 + r;     // A-operand row this lane supplies
            #pragma unroll
            for (int kc = 0; kc < 4; ++kc) {
                const int e = (c * 128 + kc * 32 + g * 8) ^ ((c & 7) << 3);
                f16x8 kf = *(const f16x8*)(&Klds[e]);
                sa = __builtin_amdgcn_mfma_f32_16x16x32_f16(kf, qf[kc], sa, 0, 0, 0);
            }
            #pragma unroll
            for (int i = 0; i < 4; ++i) s[ct * 4 + i] = sa[i] * SCALE;
        }

        // ---- causal mask (only the diagonal tile is partial) ----
        if (kt == q0) {
            #pragma unroll
            for (int ct = 0; ct < 4; ++ct)
                #pragma unroll
                for (int i = 0; i < 4; ++i) {
                    const int tk = kt + ct * 16 + g * 4 + i;
                    if (tk > sq) s[ct * 4 + i] = -1e30f;
                }
        }

        // ---- online softmax (row stats live in 4-lane groups, masks 16/32) ----
        float mx = s[0];
        #pragma unroll
        for (int i = 1; i < 16; ++i) mx = fmaxf(mx, s[i]);
        mx = fmaxf(mx, __shfl_xor(mx, 16));
        mx = fmaxf(mx, __shfl_xor(mx, 32));
        const float mnew = fmaxf(m_run, mx);
        const float corr = __expf(m_run - mnew);
        m_run = mnew;

        float ls = 0.0f;
        #pragma unroll
        for (int i = 0; i < 16; ++i) {
            const float p = __expf(s[i] - mnew);
            s[i] = p;
            ls += p;
        }
        ls += __shfl_xor(ls, 16);
        ls += __shfl_xor(ls, 32);
        l_run = l_run * corr + ls;

        // ---- rescale accumulator (acc rows are g*4+i; stats keyed by lane&15) ----
        #pragma unroll
        for (int i = 0; i < 4; ++i) {
            const float ci = __shfl(corr, (lane & 48) | (g * 4 + i));
            #pragma unroll
            for (int nb = 0; nb < 8; ++nb) acc[nb][i] *= ci;
        }

        // ---- P -> per-wave LDS (C-layout -> A-layout round trip) ----
        #pragma unroll
        for (int t = 0; t < 4; ++t) {
            h4 pb = { f2h(s[t * 4 + 0]), f2h(s[t * 4 + 1]),
                      f2h(s[t * 4 + 2]), f2h(s[t * 4 + 3]) };
            const int c0 = t * 16 + g * 4;
            const int e = (r * 64 + c0) ^ ((r & 7) << 3);
            *(h4*)(&Plds[w][e]) = pb;
        }

        // ---- O += P * V ----
        #pragma unroll
        for (int cc = 0; cc < 2; ++cc) {
            const int ep = (r * 64 + cc * 32 + g * 8) ^ ((r & 7) << 3);
            f16x8 pf = *(const f16x8*)(&Plds[w][ep]);
            #pragma unroll
            for (int nb = 0; nb < 8; ++nb) {
                const int d = nb * 16 + r;
                const int ev = (d * 64 + cc * 32 + g * 8) ^ ((d & 7) << 3);
                f16x8 vf = *(const f16x8*)(&Vlds[ev]);
                acc[nb] = __builtin_amdgcn_mfma_f32_16x16x32_f16(pf, vf, acc[nb], 0, 0, 0);
            }
        }
    }

    // ---- epilogue: normalize and store ----
    #pragma unroll
    for (int i = 0; i < 4; ++i) {
        const float li = __shfl(l_run, (lane & 48) | (g * 4 + i));
        const float rl = 1.0f / li;
        const int row = q0 + w * 16 + g * 4 + i;
        float* op = out + ((size_t)row * NBATCH + b) * (NHEAD * DHEAD) + h * DHEAD + r;
        #pragma unroll
        for (int nb = 0; nb < 8; ++nb)
            op[nb * 16] = acc[nb][i] * rl;
    }
}

extern "C" void kernel_launch(void* const* d_in, const int* in_sizes, int n_in,
                              void* d_out, int out_size, void* d_ws, size_t ws_size,
                              hipStream_t stream) {
    const float* q     = (const float*)d_in[0];
    const float* k     = (const float*)d_in[1];
    const float* v     = (const float*)d_in[2];
    const float* sinks = (const float*)d_in[3];
    float* out = (float*)d_out;

    const int nqt = SQ / 64;                       // 32 q-tiles
    dim3 grid(nqt * NBATCH * NHEAD);               // 1024 blocks
    attn_fwd<<<grid, 256, 0, stream>>>(q, k, v, sinks, out);
}

// Round 3
// 78.380 us; speedup vs baseline: 1.5245x; 1.5245x over previous
//
#include <hip/hip_runtime.h>
#include <hip/hip_bf16.h>

#define SQ 2048
#define NBATCH 2
#define NHEAD 16
#define DHEAD 128
#define NKT 32                       // 2048/64 KV tiles
#define SCALE_L2E 0.1275174609f      // (1/sqrt(128)) * log2(e)
#define LOG2E 1.4426950408889634f

typedef _Float16 f16x8 __attribute__((ext_vector_type(8)));
typedef _Float16 f16x4 __attribute__((ext_vector_type(4)));
typedef float f32x4 __attribute__((ext_vector_type(4)));

static __device__ __forceinline__ _Float16 f2h(float f) { return (_Float16)f; }

// ---------------------------------------------------------------------------
// Pre-pass: K -> fp16 tile-blocked+swizzled [b][kt][64][128]
//           V -> fp16 transposed tile-blocked+swizzled [b][kt][128][64]
// Swizzle matches the hot kernel's LDS read pattern; staging is then a pure
// linear copy (global_load_lds friendly).
// ---------------------------------------------------------------------------
__global__ __launch_bounds__(256)
void prepack(const float* __restrict__ k, const float* __restrict__ v,
             _Float16* __restrict__ kws, _Float16* __restrict__ vws) {
    const int tile  = blockIdx.x;        // 0..127
    const int which = tile >> 6;         // 0 = K, 1 = V
    const int b     = (tile >> 5) & 1;
    const int kt    = tile & 31;
    const int tid   = threadIdx.x;

    if (which == 0) {
        const float* kbase = k + (size_t)b * DHEAD + (size_t)kt * 64 * (NBATCH * DHEAD);
        _Float16* dst = kws + ((size_t)b * NKT + kt) * 8192;
        #pragma unroll
        for (int p = 0; p < 8; ++p) {
            const int id4 = tid + p * 256;          // 2048 float4 chunks
            const int row = id4 >> 5;
            const int c0  = (id4 & 31) << 2;
            f32x4 a = *(const f32x4*)(kbase + (size_t)row * (NBATCH * DHEAD) + c0);
            const int e = (row * 128 + c0) ^ ((row & 7) << 3);
            f16x4 pk = { f2h(a.x), f2h(a.y), f2h(a.z), f2h(a.w) };
            *(f16x4*)(dst + e) = pk;
        }
    } else {
        const float* vbase = v + (size_t)b * DHEAD;
        _Float16* dst = vws + ((size_t)b * NKT + kt) * 8192;
        const int d    = tid & 127;
        const int half = tid >> 7;
        #pragma unroll
        for (int p = 0; p < 8; ++p) {
            const int c0 = (p * 2 + half) * 4;
            float a0 = vbase[(size_t)(kt * 64 + c0 + 0) * (NBATCH * DHEAD) + d];
            float a1 = vbase[(size_t)(kt * 64 + c0 + 1) * (NBATCH * DHEAD) + d];
            float a2 = vbase[(size_t)(kt * 64 + c0 + 2) * (NBATCH * DHEAD) + d];
            float a3 = vbase[(size_t)(kt * 64 + c0 + 3) * (NBATCH * DHEAD) + d];
            const int e = (d * 64 + c0) ^ ((d & 7) << 3);
            f16x4 pk = { f2h(a0), f2h(a1), f2h(a2), f2h(a3) };
            *(f16x4*)(dst + e) = pk;
        }
    }
}

// ---------------------------------------------------------------------------
// Hot kernel: flash attention, 4 waves x 16 q-rows, double-buffered
// global_load_lds staging of pre-packed fp16 K/V tiles.
// ---------------------------------------------------------------------------
static __device__ __forceinline__ void gload16(const _Float16* gsrc, _Float16* ldst) {
    __builtin_amdgcn_global_load_lds(
        (const __attribute__((address_space(1))) void*)gsrc,
        (__attribute__((address_space(3))) void*)ldst, 16, 0, 0);
}

__global__ __launch_bounds__(256)
void attn_fwd(const float* __restrict__ q, const _Float16* __restrict__ kws,
              const _Float16* __restrict__ vws, const float* __restrict__ sinks,
              float* __restrict__ out) {
    __shared__ _Float16 Kb[2][8192];     // 64x128, swizzled (2x16KB)
    __shared__ _Float16 Vb[2][8192];     // 128x64, swizzled (2x16KB)
    __shared__ _Float16 Plds[4][16 * 64];

    const int tid  = threadIdx.x;
    const int w    = tid >> 6;
    const int lane = tid & 63;
    const int r    = lane & 15;
    const int g    = lane >> 4;

    const int bid = blockIdx.x;
    const int b   = bid & 1;
    const int h   = (bid >> 1) & 15;
    const int qt  = (NKT - 1) - (bid >> 5);   // heavy blocks launch first
    const int q0  = qt * 64;
    const int sq  = q0 + w * 16 + r;

    // ---- Q fragments, SCALE*log2e folded in ----
    f16x8 qf[4];
    {
        const float* qrow = q + ((size_t)sq * NBATCH + b) * (NHEAD * DHEAD) + h * DHEAD;
        #pragma unroll
        for (int kc = 0; kc < 4; ++kc) {
            const int d0 = kc * 32 + g * 8;
            f32x4 a = *(const f32x4*)(qrow + d0);
            f32x4 c = *(const f32x4*)(qrow + d0 + 4);
            f16x8 t;
            t[0] = f2h(a.x * SCALE_L2E); t[1] = f2h(a.y * SCALE_L2E);
            t[2] = f2h(a.z * SCALE_L2E); t[3] = f2h(a.w * SCALE_L2E);
            t[4] = f2h(c.x * SCALE_L2E); t[5] = f2h(c.y * SCALE_L2E);
            t[6] = f2h(c.z * SCALE_L2E); t[7] = f2h(c.w * SCALE_L2E);
            qf[kc] = t;
        }
    }

    float m_run = sinks[h] * LOG2E;   // base-2 logit space
    float l_run = 1.0f;               // sink contribution
    f32x4 acc[8];
    #pragma unroll
    for (int i = 0; i < 8; ++i) acc[i] = (f32x4)(0.0f);

    const _Float16* ktiles = kws + (size_t)b * NKT * 8192;
    const _Float16* vtiles = vws + (size_t)b * NKT * 8192;

    const int ntiles = qt + 1;

    // prologue: stage tile 0 into buf 0
    #pragma unroll
    for (int j = 0; j < 4; ++j) {
        const int off = (w * 4 + j) * 512;
        gload16(ktiles + off + lane * 8, &Kb[0][off]);
        gload16(vtiles + off + lane * 8, &Vb[0][off]);
    }
    asm volatile("s_waitcnt vmcnt(0)" ::: "memory");
    __builtin_amdgcn_s_barrier();

    for (int it = 0; it < ntiles; ++it) {
        const int cur = it & 1;
        // ---- prefetch next tile into other buffer ----
        if (it + 1 < ntiles) {
            const _Float16* kt_n = ktiles + (size_t)(it + 1) * 8192;
            const _Float16* vt_n = vtiles + (size_t)(it + 1) * 8192;
            #pragma unroll
            for (int j = 0; j < 4; ++j) {
                const int off = (w * 4 + j) * 512;
                gload16(kt_n + off + lane * 8, &Kb[cur ^ 1][off]);
                gload16(vt_n + off + lane * 8, &Vb[cur ^ 1][off]);
            }
        }

        // ---- S^T = K * Q^T ----
        float s[16];
        #pragma unroll
        for (int ct = 0; ct < 4; ++ct) {
            f32x4 sa = (f32x4)(0.0f);
            const int c = ct * 16 + r;
            #pragma unroll
            for (int kc = 0; kc < 4; ++kc) {
                const int e = (c * 128 + kc * 32 + g * 8) ^ ((c & 7) << 3);
                f16x8 kf = *(const f16x8*)(&Kb[cur][e]);
                sa = __builtin_amdgcn_mfma_f32_16x16x32_f16(kf, qf[kc], sa, 0, 0, 0);
            }
            #pragma unroll
            for (int i = 0; i < 4; ++i) s[ct * 4 + i] = sa[i];
        }

        // ---- causal mask (diagonal tile only) ----
        if (it == qt) {
            #pragma unroll
            for (int ct = 0; ct < 4; ++ct)
                #pragma unroll
                for (int i = 0; i < 4; ++i) {
                    const int tk = q0 + ct * 16 + g * 4 + i;
                    if (tk > sq) s[ct * 4 + i] = -1e30f;
                }
        }

        // ---- online softmax (base-2) ----
        float mx = s[0];
        #pragma unroll
        for (int i = 1; i < 16; ++i) mx = fmaxf(mx, s[i]);
        mx = fmaxf(mx, __shfl_xor(mx, 16));
        mx = fmaxf(mx, __shfl_xor(mx, 32));
        const float mnew = fmaxf(m_run, mx);
        const float corr = __builtin_amdgcn_exp2f(m_run - mnew);
        m_run = mnew;

        float ls = 0.0f;
        #pragma unroll
        for (int i = 0; i < 16; ++i) {
            const float p = __builtin_amdgcn_exp2f(s[i] - mnew);
            s[i] = p;
            ls += p;
        }
        ls += __shfl_xor(ls, 16);
        ls += __shfl_xor(ls, 32);
        l_run = l_run * corr + ls;

        // ---- rescale accumulator ----
        #pragma unroll
        for (int i = 0; i < 4; ++i) {
            const float ci = __shfl(corr, (lane & 48) | (g * 4 + i));
            #pragma unroll
            for (int nb = 0; nb < 8; ++nb) acc[nb][i] *= ci;
        }

        // ---- P -> per-wave LDS (C-layout -> A-layout) ----
        #pragma unroll
        for (int t = 0; t < 4; ++t) {
            f16x4 pb = { f2h(s[t * 4 + 0]), f2h(s[t * 4 + 1]),
                         f2h(s[t * 4 + 2]), f2h(s[t * 4 + 3]) };
            const int c0 = t * 16 + g * 4;
            const int e = (r * 64 + c0) ^ ((r & 7) << 3);
            *(f16x4*)(&Plds[w][e]) = pb;
        }

        // ---- O += P * V ----
        #pragma unroll
        for (int cc = 0; cc < 2; ++cc) {
            const int ep = (r * 64 + cc * 32 + g * 8) ^ ((r & 7) << 3);
            f16x8 pf = *(const f16x8*)(&Plds[w][ep]);
            #pragma unroll
            for (int nb = 0; nb < 8; ++nb) {
                const int d = nb * 16 + r;
                const int ev = (d * 64 + cc * 32 + g * 8) ^ ((d & 7) << 3);
                f16x8 vf = *(const f16x8*)(&Vb[cur][ev]);
                acc[nb] = __builtin_amdgcn_mfma_f32_16x16x32_f16(pf, vf, acc[nb], 0, 0, 0);
            }
        }

        // ---- drain prefetch, release buffers ----
        asm volatile("s_waitcnt vmcnt(0)" ::: "memory");
        __builtin_amdgcn_s_barrier();
        asm volatile("" ::: "memory");
    }

    // ---- epilogue ----
    #pragma unroll
    for (int i = 0; i < 4; ++i) {
        const float li = __shfl(l_run, (lane & 48) | (g * 4 + i));
        const float rl = 1.0f / li;
        const int row = q0 + w * 16 + g * 4 + i;
        float* op = out + ((size_t)row * NBATCH + b) * (NHEAD * DHEAD) + h * DHEAD + r;
        #pragma unroll
        for (int nb = 0; nb < 8; ++nb)
            op[nb * 16] = acc[nb][i] * rl;
    }
}

extern "C" void kernel_launch(void* const* d_in, const int* in_sizes, int n_in,
                              void* d_out, int out_size, void* d_ws, size_t ws_size,
                              hipStream_t stream) {
    const float* q     = (const float*)d_in[0];
    const float* k     = (const float*)d_in[1];
    const float* v     = (const float*)d_in[2];
    const float* sinks = (const float*)d_in[3];
    float* out = (float*)d_out;

    _Float16* kws = (_Float16*)d_ws;                        // 1 MB
    _Float16* vws = kws + (size_t)NBATCH * NKT * 8192;      // 1 MB

    prepack<<<dim3(128), 256, 0, stream>>>(k, v, kws, vws);
    attn_fwd<<<dim3(NKT * NBATCH * NHEAD), 256, 0, stream>>>(q, kws, vws, sinks, out);
}